// Round 13
// baseline (549.510 us; speedup 1.0000x reference)
//
#include <hip/hip_runtime.h>
#include <hip/hip_bf16.h>

#define BB 2
#define HH 192
#define WIMG 192
#define CC 192
#define NHEADS 6
#define HD 32
#define NTOK (HH*WIMG)        // 36864 tokens per image
#define NWX 24                // windows per axis
#define NWIN 576
#define BWIN (BB*NWIN)        // 1152
#define MLPH 768
#define EPS_ 1e-5f
#define NSIDE_TOK (BB*NTOK)   // 73728 tokens per side

typedef __attribute__((ext_vector_type(8))) short bf16x8;
typedef __attribute__((ext_vector_type(4))) float f32x4;
typedef __attribute__((ext_vector_type(16))) float f32x16;

#define GLOBAL_AS __attribute__((address_space(1)))
#define LDS_AS __attribute__((address_space(3)))
__device__ __forceinline__ void gll16(const void* g, void* l) {
    __builtin_amdgcn_global_load_lds((const GLOBAL_AS unsigned int*)g,
                                     (LDS_AS unsigned int*)l, 16, 0, 0);
}

__device__ __forceinline__ unsigned short f2bf(float f) {
    __hip_bfloat16 h = __float2bfloat16(f);
    return *reinterpret_cast<unsigned short*>(&h);
}
__device__ __forceinline__ float bfu(unsigned short u) {
    return __uint_as_float(((unsigned int)u) << 16);
}
// tanh-form GELU (max |err| vs exact ~3e-3; threshold 0.18)
__device__ __forceinline__ float gelu_fast(float x) {
    float z = 1.5957691216f*(x + 0.044715f*x*x*x);
    float e = __expf(z);
    float t = 1.0f - 2.0f/(e + 1.0f);
    return 0.5f*x*(1.0f + t);
}
// shifted-window token index for window (wi,wj), position p in [0,64)
__device__ __forceinline__ int tokof(int b, int wi, int wj, int p) {
    int rh = wi*8 + (p>>3), rw = wj*8 + (p&7);
    int i = rh + 4; if (i >= HH) i -= HH;
    int j = rw + 4; if (j >= WIMG) j -= WIMG;
    return b*NTOK + i*WIMG + j;
}

// ---------------- K1: LayerNorm1 -> bf16 ----------------
__global__ __launch_bounds__(256) void ln1_kernel(
    const float* __restrict__ xl, const float* __restrict__ xr,
    const float* __restrict__ g, const float* __restrict__ bta,
    __hip_bfloat16* __restrict__ xln_all)
{
    int token = blockIdx.x*4 + (threadIdx.x >> 6);
    int lane = threadIdx.x & 63;
    const float* src;
    __hip_bfloat16* dst;
    if (token < NSIDE_TOK) { src = xl + (size_t)token*CC; dst = xln_all + (size_t)token*CC; }
    else { int t2 = token - NSIDE_TOK; src = xr + (size_t)t2*CC; dst = xln_all + (size_t)token*CC; }
    float v0 = src[lane], v1 = src[lane+64], v2 = src[lane+128];
    float s = v0+v1+v2;
    float q = v0*v0 + v1*v1 + v2*v2;
    #pragma unroll
    for (int m = 32; m; m >>= 1) { s += __shfl_xor(s, m, 64); q += __shfl_xor(q, m, 64); }
    float mu = s * (1.0f/CC);
    float inv = rsqrtf(fmaxf(q*(1.0f/CC) - mu*mu, 0.0f) + EPS_);
    dst[lane]     = __float2bfloat16((v0-mu)*inv*g[lane]     + bta[lane]);
    dst[lane+64]  = __float2bfloat16((v1-mu)*inv*g[lane+64]  + bta[lane+64]);
    dst[lane+128] = __float2bfloat16((v2-mu)*inv*g[lane+128] + bta[lane+128]);
}

// ---------------- K2: epipolar gather index map ----------------
__global__ __launch_bounds__(256) void map_kernel(
    const float* __restrict__ d_left, const float* __restrict__ d_right,
    int* __restrict__ map)
{
    int gid = blockIdx.x*256 + threadIdx.x;      // 0 .. 2*73728
    int side = (gid >= NSIDE_TOK) ? 1 : 0;
    int row = gid - side*NSIDE_TOK;
    int j = row % WIMG;
    float d = side ? d_right[row] : d_left[row];
    int jj;
    if (!side) { float f = (float)j + 0.5f - d; f = fmaxf(f, 0.f); jj = (int)f; }
    else       { float f = (float)j + 0.5f + d; f = fminf(f, 191.f); jj = (int)f; }
    map[gid] = (side ? 0 : NSIDE_TOK) + row - j + jj;
}

// ---------------- K3: convert weights to bf16 MFMA-FRAGMENT order ----------
// q_wf/kv_wf/proj_f: 16x16 frags (unchanged). W1f/W2f: 32x32x16 frags:
// B-frag lane l elem j: n = tile*32 + (l&31), k = kstep*16 + (l>>5)*8 + j.
__global__ __launch_bounds__(256) void conv_w_kernel(
    const float* __restrict__ q_w, const float* __restrict__ kv_w,
    const float* __restrict__ proj_w, const float* __restrict__ fc1_w,
    const float* __restrict__ fc2_w,
    __hip_bfloat16* __restrict__ q_wf, __hip_bfloat16* __restrict__ kv_wf,
    __hip_bfloat16* __restrict__ proj_f, __hip_bfloat16* __restrict__ W1f,
    __hip_bfloat16* __restrict__ W2f)
{
    int idx = blockIdx.x*256 + threadIdx.x;   // total 442368
    if (idx < 36864) {
        int j = idx & 7, lane = (idx>>3) & 63, fr = idx>>9;
        int ct = fr % 12, ks = fr / 12;
        int n = ct*16 + (lane&15), k = ks*32 + (lane>>4)*8 + j;
        q_wf[idx] = __float2bfloat16(q_w[(size_t)k*192 + n]);
    } else if (idx < 110592) {
        int i2 = idx - 36864;
        int j = i2 & 7, lane = (i2>>3) & 63, fr = i2>>9;
        int ct = fr % 24, ks = fr / 24;
        int n = ct*16 + (lane&15), k = ks*32 + (lane>>4)*8 + j;
        kv_wf[i2] = __float2bfloat16(kv_w[(size_t)k*384 + n]);
    } else if (idx < 147456) {
        int i2 = idx - 110592;
        int j = i2 & 7, lane = (i2>>3) & 63, fr = i2>>9;
        int ct = fr % 12, h = fr / 12;
        int n = ct*16 + (lane&15), k = h*32 + (lane>>4)*8 + j;
        proj_f[i2] = __float2bfloat16(proj_w[(size_t)k*192 + n]);
    } else if (idx < 294912) {
        // W1f: chunk cc (24KB, 24 frags): frag = ch*12 + ks (ch=col-half, ks=kstep16)
        int i2 = idx - 147456;
        int j = i2 & 7, l = (i2>>3) & 63, fr = i2>>9;   // fr 0..575
        int cc = fr / 24, r = fr % 24;
        int ch = r / 12, ks = r % 12;
        int n = cc*64 + ch*32 + (l&31), k = ks*16 + (l>>5)*8 + j;
        W1f[i2] = __float2bfloat16(fc1_w[(size_t)k*MLPH + n]);
    } else {
        // W2f: chunk cc (24KB, 24 frags): frag = ct6*4 + ks (ct6=col-tile of 32)
        int i2 = idx - 294912;
        int j = i2 & 7, l = (i2>>3) & 63, fr = i2>>9;
        int cc = fr / 24, r = fr % 24;
        int ct6 = r / 4, ks = r % 4;
        int n = ct6*32 + (l&31), k = cc*64 + ks*16 + (l>>5)*8 + j;
        W2f[i2] = __float2bfloat16(fc2_w[(size_t)k*192 + n]);
    }
}

// ---------------- K4: per-head rel-pos bias matrix [6][64][64] f32 ----------
__global__ __launch_bounds__(256) void bias_setup_kernel(
    const float* __restrict__ table, float* __restrict__ bias_glob)
{
    int idx = blockIdx.x*256 + threadIdx.x;   // 24576
    int h = idx >> 12, rem = idx & 4095;
    int q = rem >> 6, k = rem & 63;
    int qy = q>>3, qx = q&7, ky = k>>3, kx = k&7;
    int ridx = (qy-ky+7)*15 + (qx-kx+7);
    bias_glob[idx] = table[ridx*NHEADS + h];
}

// ---------------- K5: bf16 MFMA projection GEMM (A in regs, W staged in LDS)
template<int NT>
__global__ __launch_bounds__(256) void proj_gemm_kernel(
    const __hip_bfloat16* __restrict__ in, const __hip_bfloat16* __restrict__ Wf,
    const float* __restrict__ bias, const int* __restrict__ map,
    __hip_bfloat16* __restrict__ outp, float scale)
{
    __shared__ unsigned short wst[2][NT*512];
    const int tid = threadIdx.x, lane = tid & 63, w = tid >> 6;
    const int r16 = lane & 15, kg = lane >> 4, w16 = w*16;
    const size_t baserow = (size_t)blockIdx.x * 64;
    const int row = (int)baserow + w16 + r16;
    const size_t arow = map ? (size_t)map[row] : (size_t)row;

    bf16x8 aReg[6];
    #pragma unroll
    for (int ks = 0; ks < 6; ++ks)
        aReg[ks] = *reinterpret_cast<const bf16x8*>(in + arow*CC + ks*32 + kg*8);

    const char* wsrc = (const char*)Wf;
    const int soff = w*1024 + lane*16;
    #pragma unroll
    for (int i = 0; i < NT/4; ++i)
        gll16(wsrc + i*4096 + soff, (char*)wst[0] + i*4096 + w*1024);

    f32x4 acc[NT];
    #pragma unroll
    for (int ct = 0; ct < NT; ++ct) { float bv = bias[ct*16+r16]; acc[ct] = (f32x4){bv,bv,bv,bv}; }

    #pragma unroll
    for (int ks = 0; ks < 6; ++ks) {
        __syncthreads();
        if (ks < 5) {
            const char* s2 = wsrc + (size_t)(ks+1)*NT*1024;
            #pragma unroll
            for (int i = 0; i < NT/4; ++i)
                gll16(s2 + i*4096 + soff, (char*)wst[(ks+1)&1] + i*4096 + w*1024);
        }
        #pragma unroll
        for (int ct = 0; ct < NT; ++ct) {
            bf16x8 bb = *reinterpret_cast<const bf16x8*>(wst[ks&1] + ct*512 + lane*8);
            acc[ct] = __builtin_amdgcn_mfma_f32_16x16x32_bf16(aReg[ks], bb, acc[ct], 0, 0, 0);
        }
    }
    const int ldo = NT*16;
    #pragma unroll
    for (int ct = 0; ct < NT; ++ct)
        #pragma unroll
        for (int r = 0; r < 4; ++r)
            outp[(baserow + w16 + kg*4 + r)*ldo + ct*16 + r16] =
                __float2bfloat16(acc[ct][r] * scale);
}

// ---------------- K6: window attention + m, one barrier ---------------------
__global__ __launch_bounds__(128) void attn_pm_kernel(
    const __hip_bfloat16* __restrict__ Qglob,   // [2][73728][192]
    const __hip_bfloat16* __restrict__ KVglob,  // [2][73728][384]
    const float* __restrict__ bias_glob,        // [6][64][64]
    __hip_bfloat16* __restrict__ Og,            // [2*1152*64][192]
    float* __restrict__ mg)                     // [2][1152][6][64]
{
    __shared__ unsigned short Pl[2][64*72];
    __shared__ unsigned short Vl[2][32*72];
    const int tid = threadIdx.x, lane = tid & 63, s = tid >> 6;
    const int r16 = lane & 15, kg = lane >> 4;
    const int bid = blockIdx.x;
    const int wd = bid / NHEADS, h = bid % NHEADS;
    const int b = wd / NWIN, win = wd % NWIN;
    const int wi = win / NWX, wj = win % NWX;
    const bool edge_i = (wi == NWX-1), edge_j = (wj == NWX-1);

    const __hip_bfloat16* Qs  = Qglob  + (size_t)s*NSIDE_TOK*CC;
    const __hip_bfloat16* KVs = KVglob + (size_t)s*NSIDE_TOK*(2*CC);

    int tokQ[4];
    #pragma unroll
    for (int mi = 0; mi < 4; ++mi) tokQ[mi] = tokof(b, wi, wj, mi*16 + r16);
    const int tokV = tokof(b, wi, wj, lane);

    unsigned short* P = Pl[s];
    unsigned short* V = Vl[s];

    // ---- stage V^T (wave-private)
    {
        bf16x8 vv[4];
        #pragma unroll
        for (int dg = 0; dg < 4; ++dg)
            vv[dg] = *reinterpret_cast<const bf16x8*>(
                KVs + (size_t)tokV*(2*CC) + CC + h*HD + dg*8);
        #pragma unroll
        for (int dg = 0; dg < 4; ++dg)
            #pragma unroll
            for (int jj = 0; jj < 8; ++jj)
                V[(dg*8+jj)*72 + lane] = (unsigned short)vv[dg][jj];
    }

    // ---- S = Q K^T
    bf16x8 aQ[4], bK[4];
    #pragma unroll
    for (int mi = 0; mi < 4; ++mi)
        aQ[mi] = *reinterpret_cast<const bf16x8*>(
            Qs + (size_t)tokQ[mi]*CC + h*HD + kg*8);
    #pragma unroll
    for (int ni = 0; ni < 4; ++ni)
        bK[ni] = *reinterpret_cast<const bf16x8*>(
            KVs + (size_t)tokQ[ni]*(2*CC) + h*HD + kg*8);
    f32x4 S[4][4];
    #pragma unroll
    for (int mi = 0; mi < 4; ++mi)
        #pragma unroll
        for (int ni = 0; ni < 4; ++ni)
            S[mi][ni] = __builtin_amdgcn_mfma_f32_16x16x32_bf16(
                aQ[mi], bK[ni], (f32x4){0.f,0.f,0.f,0.f}, 0, 0, 0);

    // ---- bias + shift mask
    #pragma unroll
    for (int mi = 0; mi < 4; ++mi)
        #pragma unroll
        for (int ni = 0; ni < 4; ++ni)
            #pragma unroll
            for (int rr = 0; rr < 4; ++rr) {
                int q = mi*16 + kg*4 + rr, k = ni*16 + r16;
                float bm = bias_glob[h*4096 + q*64 + k];
                int qy = q>>3, qx = q&7, ky = k>>3, kx = k&7;
                bool msk = (edge_i && ((qy<4) != (ky<4))) ||
                           (edge_j && ((qx<4) != (kx<4)));
                S[mi][ni][rr] += bm + (msk ? -100.0f : 0.0f);
            }

    // ---- softmax over k
    float mx[4][4], sm[4][4];
    #pragma unroll
    for (int mi = 0; mi < 4; ++mi)
        #pragma unroll
        for (int rr = 0; rr < 4; ++rr)
            mx[mi][rr] = fmaxf(fmaxf(S[mi][0][rr], S[mi][1][rr]),
                               fmaxf(S[mi][2][rr], S[mi][3][rr]));
    #pragma unroll
    for (int m = 1; m <= 8; m <<= 1)
        #pragma unroll
        for (int mi = 0; mi < 4; ++mi)
            #pragma unroll
            for (int rr = 0; rr < 4; ++rr)
                mx[mi][rr] = fmaxf(mx[mi][rr], __shfl_xor(mx[mi][rr], m, 64));
    #pragma unroll
    for (int mi = 0; mi < 4; ++mi)
        #pragma unroll
        for (int rr = 0; rr < 4; ++rr) sm[mi][rr] = 0.f;
    #pragma unroll
    for (int mi = 0; mi < 4; ++mi)
        #pragma unroll
        for (int ni = 0; ni < 4; ++ni)
            #pragma unroll
            for (int rr = 0; rr < 4; ++rr) {
                S[mi][ni][rr] = __expf(S[mi][ni][rr] - mx[mi][rr]);
                sm[mi][rr] += S[mi][ni][rr];
            }
    #pragma unroll
    for (int m = 1; m <= 8; m <<= 1)
        #pragma unroll
        for (int mi = 0; mi < 4; ++mi)
            #pragma unroll
            for (int rr = 0; rr < 4; ++rr)
                sm[mi][rr] += __shfl_xor(sm[mi][rr], m, 64);
    #pragma unroll
    for (int mi = 0; mi < 4; ++mi)
        #pragma unroll
        for (int rr = 0; rr < 4; ++rr) sm[mi][rr] = 1.0f / sm[mi][rr];

    // ---- P -> LDS (72-stride rows)
    #pragma unroll
    for (int mi = 0; mi < 4; ++mi)
        #pragma unroll
        for (int ni = 0; ni < 4; ++ni)
            #pragma unroll
            for (int rr = 0; rr < 4; ++rr)
                P[(mi*16 + kg*4 + rr)*72 + ni*16 + r16] =
                    f2bf(S[mi][ni][rr] * sm[mi][rr]);

    // ---- PV (own P, own V^T)
    {
        f32x4 O[4][2];
        #pragma unroll
        for (int mi = 0; mi < 4; ++mi)
            #pragma unroll
            for (int dt = 0; dt < 2; ++dt) O[mi][dt] = (f32x4){0.f,0.f,0.f,0.f};
        #pragma unroll
        for (int ks = 0; ks < 2; ++ks) {
            bf16x8 aP[4], bV[2];
            #pragma unroll
            for (int mi = 0; mi < 4; ++mi)
                aP[mi] = *reinterpret_cast<const bf16x8*>(
                    P + (mi*16 + r16)*72 + ks*32 + kg*8);
            #pragma unroll
            for (int dt = 0; dt < 2; ++dt)
                bV[dt] = *reinterpret_cast<const bf16x8*>(
                    V + (dt*16 + r16)*72 + ks*32 + kg*8);
            #pragma unroll
            for (int mi = 0; mi < 4; ++mi)
                #pragma unroll
                for (int dt = 0; dt < 2; ++dt)
                    O[mi][dt] = __builtin_amdgcn_mfma_f32_16x16x32_bf16(
                        aP[mi], bV[dt], O[mi][dt], 0, 0, 0);
        }
        __hip_bfloat16* ob = Og + ((size_t)(s*BWIN + wd)*64)*CC + h*HD;
        #pragma unroll
        for (int mi = 0; mi < 4; ++mi)
            #pragma unroll
            for (int dt = 0; dt < 2; ++dt)
                #pragma unroll
                for (int rr = 0; rr < 4; ++rr)
                    ob[(size_t)(mi*16 + kg*4 + rr)*CC + dt*16 + r16] =
                        __float2bfloat16(O[mi][dt][rr]);
    }

    __syncthreads();   // both waves' P visible

    // ---- m: wave s computes m for side s (P at native 72 stride)
    {
        const unsigned short* Pa = Pl[s];
        const unsigned short* Pb = Pl[s^1];
        const int i = lane;
        const int s0 = (i >= 2) ? -2 : -i;
        const int s1 = (i <= 61) ? 2 : 63 - i;
        float acc = 0.f;
        for (int k = 0; k < 64; k += 2) {
            float pb0 = bfu(Pb[k*72 + i]);
            float pb1 = bfu(Pb[(k+1)*72 + i]);
            float a0 = 0.f, a1 = 0.f;
            for (int ss = s0; ss <= s1; ++ss) {
                unsigned int pr = *reinterpret_cast<const unsigned int*>(
                    &Pa[(i+ss)*72 + k]);
                a0 += bfu((unsigned short)(pr & 0xffff));
                a1 += bfu((unsigned short)(pr >> 16));
            }
            acc += a0*pb0 + a1*pb1;
        }
        float e = __expf(10.0f * acc);           // tanh(5a), a >= 0
        mg[((size_t)(s*BWIN + wd)*NHEADS + h)*64 + i] = 1.0f - 2.0f/(e + 1.0f);
    }
}

// ---------------- K7: proj + fuse + reverse + residual + LN2 -> xln2 --------
__global__ __launch_bounds__(256) void projfuse_kernel(
    const __hip_bfloat16* __restrict__ Og,
    const __hip_bfloat16* __restrict__ proj_f,
    const float* __restrict__ proj_b,
    const float* __restrict__ mg,
    const __hip_bfloat16* __restrict__ xln_all,
    const float* __restrict__ x_left, const float* __restrict__ x_right,
    const float* __restrict__ g2, const float* __restrict__ b2,
    float* __restrict__ out, __hip_bfloat16* __restrict__ xln2)
{
    __shared__ unsigned short wst[2][12*512];
    const int tid = threadIdx.x, lane = tid & 63, w = tid >> 6;
    const int r16 = lane & 15, kg = lane >> 4, w16 = w*16;
    const int bid = blockIdx.x;
    const int s = bid / BWIN, wd = bid % BWIN;
    const int b = wd / NWIN, win = wd % NWIN;
    const int wi = win / NWX, wj = win % NWX;

    const size_t orow = (size_t)(s*BWIN + wd)*64 + w16 + r16;
    bf16x8 aReg[6];
    #pragma unroll
    for (int ks = 0; ks < 6; ++ks)
        aReg[ks] = *reinterpret_cast<const bf16x8*>(Og + orow*CC + ks*32 + kg*8);

    const char* wsrc = (const char*)proj_f;
    const int soff = w*1024 + lane*16;
    #pragma unroll
    for (int i = 0; i < 3; ++i)
        gll16(wsrc + i*4096 + soff, (char*)wst[0] + i*4096 + w*1024);

    f32x4 acc[12];
    #pragma unroll
    for (int ct = 0; ct < 12; ++ct) { float bv = proj_b[ct*16+r16]; acc[ct] = (f32x4){bv,bv,bv,bv}; }

    #pragma unroll
    for (int ks = 0; ks < 6; ++ks) {
        __syncthreads();
        if (ks < 5) {
            const char* s2 = wsrc + (size_t)(ks+1)*12288;
            #pragma unroll
            for (int i = 0; i < 3; ++i)
                gll16(s2 + i*4096 + soff, (char*)wst[(ks+1)&1] + i*4096 + w*1024);
        }
        #pragma unroll
        for (int ct = 0; ct < 12; ++ct) {
            bf16x8 bb = *reinterpret_cast<const bf16x8*>(wst[ks&1] + ct*512 + lane*8);
            acc[ct] = __builtin_amdgcn_mfma_f32_16x16x32_bf16(aReg[ks], bb, acc[ct], 0, 0, 0);
        }
    }

    // ---- epilogue: fuse + window reverse + residual (keep values in acc)
    int tk[4];
    #pragma unroll
    for (int rr = 0; rr < 4; ++rr) tk[rr] = tokof(b, wi, wj, w16 + kg*4 + rr);
    const float* xo_s = s ? x_right : x_left;
    const __hip_bfloat16* xw_s = xln_all + (size_t)s*NSIDE_TOK*CC;
    float* out_s = out + (size_t)s*NSIDE_TOK*CC;
    __hip_bfloat16* xln2_s = xln2 + (size_t)s*NSIDE_TOK*CC;
    const float* mrow = mg + (size_t)(s*BWIN + wd)*NHEADS*64;

    float g2c[12], b2c[12];
    #pragma unroll
    for (int ct = 0; ct < 12; ++ct) {
        g2c[ct] = g2[ct*16 + r16];
        b2c[ct] = b2[ct*16 + r16];
    }

    #pragma unroll
    for (int ct = 0; ct < 12; ++ct) {
        int col = ct*16 + r16;
        int h = ct >> 1;
        #pragma unroll
        for (int rr = 0; rr < 4; ++rr) {
            int q = w16 + kg*4 + rr;
            size_t tt = (size_t)tk[rr];
            float m = mrow[h*64 + q];
            float xw = __bfloat162float(xw_s[tt*CC + col]);
            float p = acc[ct][rr];
            float val = xo_s[tt*CC + col] + xw + (p - xw)*m;
            out_s[tt*CC + col] = val;
            acc[ct][rr] = val;
        }
    }

    // ---- LN2 of fused output -> bf16 xln2 (stats via 16-lane shuffles)
    #pragma unroll
    for (int rr = 0; rr < 4; ++rr) {
        float sum = 0.f, sq = 0.f;
        #pragma unroll
        for (int ct = 0; ct < 12; ++ct) {
            float v = acc[ct][rr];
            sum += v; sq += v*v;
        }
        #pragma unroll
        for (int m = 1; m <= 8; m <<= 1) {
            sum += __shfl_xor(sum, m, 64);
            sq  += __shfl_xor(sq,  m, 64);
        }
        float mu = sum * (1.0f/CC);
        float inv = rsqrtf(fmaxf(sq*(1.0f/CC) - mu*mu, 0.0f) + EPS_);
        size_t tt = (size_t)tk[rr];
        #pragma unroll
        for (int ct = 0; ct < 12; ++ct) {
            unsigned short uv = f2bf((acc[ct][rr]-mu)*inv*g2c[ct] + b2c[ct]);
            *reinterpret_cast<unsigned short*>(&xln2_s[tt*CC + ct*16 + r16]) = uv;
        }
    }
}

// ---------------- K8: fused MLP via 32x32x16 MFMA, 24 phases ----------------
// 64 tokens/block, 4 waves: wave w -> row-tile rt=w&1 (32 tokens), col-half
// ch=w>>1. Per cc: phase A (fc1: 12 MFMAs from 24KB W1 chunk), phase B (fc2:
// 12 MFMAs over 3 col-tiles from 24KB W2 chunk). 2x FLOP per B-frag read vs
// 16x16 -> half the phases/barriers/LDS-reads/MFMA instrs.
__global__ __launch_bounds__(256) void mlp_mfma_kernel(
    float* __restrict__ out, const __hip_bfloat16* __restrict__ xln2,
    const __hip_bfloat16* __restrict__ W1f, const float* __restrict__ fc1_b,
    const __hip_bfloat16* __restrict__ W2f, const float* __restrict__ fc2_b)
{
    __shared__ unsigned short hbuf[64*72];     // 9216 B
    __shared__ unsigned short wst[2][12288];   // 2 x 24576 B weight staging
    const int tid  = threadIdx.x;
    const int lane = tid & 63;
    const int w    = tid >> 6;
    const int c32 = lane & 31, kg2 = lane >> 5;
    const int rt = w & 1, ch = w >> 1;
    const size_t base = (size_t)blockIdx.x * 64 * CC;
    const int arow = rt*32 + c32;

    // A-frags for fc1: 12 ksteps of 16 (row=lane&31, k=(lane>>5)*8+j)
    bf16x8 aReg[12];
    #pragma unroll
    for (int ks = 0; ks < 12; ++ks)
        aReg[ks] = *reinterpret_cast<const bf16x8*>(
            xln2 + base + (size_t)arow*CC + ks*16 + kg2*8);

    const char* W1c = (const char*)W1f;   // 12 chunks x 24576 B
    const char* W2c = (const char*)W2f;
    const int soff = w*1024 + lane*16;
    const int doff = w*1024;

    // prologue: stage W1 chunk 0 -> wst[0] (6 issues of 4KB)
    #pragma unroll
    for (int i = 0; i < 6; ++i)
        gll16(W1c + i*4096 + soff, (char*)wst[0] + i*4096 + doff);

    f32x16 acc2[3];
    #pragma unroll
    for (int t3 = 0; t3 < 3; ++t3)
        #pragma unroll
        for (int r = 0; r < 16; ++r) acc2[t3][r] = 0.f;

    for (int cc = 0; cc < 12; ++cc) {
        // ---- phase A: stage W2 chunk cc -> wst[1]; compute fc1 from wst[0]
        __builtin_amdgcn_s_barrier();
        {
            const char* s2 = W2c + (size_t)cc*24576;
            #pragma unroll
            for (int i = 0; i < 6; ++i)
                gll16(s2 + i*4096 + soff, (char*)wst[1] + i*4096 + doff);
        }
        asm volatile("s_waitcnt vmcnt(6)" ::: "memory");
        __builtin_amdgcn_s_barrier();
        f32x16 acc1;
        {
            float bv = fc1_b[cc*64 + ch*32 + c32];
            #pragma unroll
            for (int r = 0; r < 16; ++r) acc1[r] = bv;
        }
        #pragma unroll
        for (int ks = 0; ks < 12; ++ks) {
            bf16x8 bw = *reinterpret_cast<const bf16x8*>(
                wst[0] + (ch*12 + ks)*512 + lane*8);
            acc1 = __builtin_amdgcn_mfma_f32_32x32x16_bf16(aReg[ks], bw, acc1, 0, 0, 0);
        }
        // GELU -> hbuf (C layout: col=lane&31, row=(r&3)+8*(r>>2)+4*kg2)
        #pragma unroll
        for (int r = 0; r < 16; ++r) {
            int row = rt*32 + (r&3) + 8*(r>>2) + 4*kg2;
            hbuf[row*72 + ch*32 + c32] = f2bf(gelu_fast(acc1[r]));
        }
        // ---- phase B: stage W1 chunk cc+1 -> wst[0]; compute fc2 from wst[1]
        __builtin_amdgcn_s_barrier();
        if (cc < 11) {
            const char* s2 = W1c + (size_t)(cc+1)*24576;
            #pragma unroll
            for (int i = 0; i < 6; ++i)
                gll16(s2 + i*4096 + soff, (char*)wst[0] + i*4096 + doff);
            asm volatile("s_waitcnt vmcnt(6)" ::: "memory");
        } else {
            asm volatile("s_waitcnt vmcnt(0)" ::: "memory");
        }
        __builtin_amdgcn_s_barrier();
        bf16x8 aH[4];
        #pragma unroll
        for (int ks = 0; ks < 4; ++ks)
            aH[ks] = *reinterpret_cast<const bf16x8*>(
                hbuf + arow*72 + ks*16 + kg2*8);
        #pragma unroll
        for (int t3 = 0; t3 < 3; ++t3) {
            const int ct6 = ch*3 + t3;
            #pragma unroll
            for (int ks = 0; ks < 4; ++ks) {
                bf16x8 bw = *reinterpret_cast<const bf16x8*>(
                    wst[1] + (ct6*4 + ks)*512 + lane*8);
                acc2[t3] = __builtin_amdgcn_mfma_f32_32x32x16_bf16(aH[ks], bw, acc2[t3], 0, 0, 0);
            }
        }
    }

    // epilogue: out += mlp + fc2_b
    #pragma unroll
    for (int t3 = 0; t3 < 3; ++t3) {
        int colb = (ch*3 + t3)*32 + c32;
        float bv = fc2_b[colb];
        #pragma unroll
        for (int r = 0; r < 16; ++r) {
            int row = rt*32 + (r&3) + 8*(r>>2) + 4*kg2;
            size_t idx = base + (size_t)row*CC + colb;
            out[idx] = out[idx] + acc2[t3][r] + bv;
        }
    }
}

// ---------------- launch ----------------
extern "C" void kernel_launch(void* const* d_in, const int* in_sizes, int n_in,
                              void* d_out, int out_size, void* d_ws, size_t ws_size,
                              hipStream_t stream)
{
    (void)in_sizes; (void)n_in; (void)out_size; (void)ws_size;
    const float* x_left  = (const float*)d_in[0];
    const float* x_right = (const float*)d_in[1];
    const float* d_left  = (const float*)d_in[2];
    const float* d_right = (const float*)d_in[3];
    const float* n1g = (const float*)d_in[4];
    const float* n1b = (const float*)d_in[5];
    const float* q_w = (const float*)d_in[6];
    const float* q_b = (const float*)d_in[7];
    const float* kv_w = (const float*)d_in[8];
    const float* kv_b = (const float*)d_in[9];
    const float* proj_w = (const float*)d_in[10];
    const float* proj_b = (const float*)d_in[11];
    const float* bias_table = (const float*)d_in[12];
    const float* n2g = (const float*)d_in[13];
    const float* n2b = (const float*)d_in[14];
    const float* fc1_w = (const float*)d_in[15];
    const float* fc1_b = (const float*)d_in[16];
    const float* fc2_w = (const float*)d_in[17];
    const float* fc2_b = (const float*)d_in[18];
    float* out = (float*)d_out;

    char* ws = (char*)d_ws;
    __hip_bfloat16* xln_all  = (__hip_bfloat16*)(ws);                 // 56623104 B
    __hip_bfloat16* Qg       = (__hip_bfloat16*)(ws + 56623104);      // 56623104 B
    __hip_bfloat16* KVg      = (__hip_bfloat16*)(ws + 113246208);     // 113246208 B
    __hip_bfloat16* xln2     = (__hip_bfloat16*)(ws + 113246208);     // aliases KVg (dead after attn)
    __hip_bfloat16* q_wf     = (__hip_bfloat16*)(ws + 226492416);     // 73728 B
    __hip_bfloat16* kv_wf    = (__hip_bfloat16*)(ws + 226566144);     // 147456 B
    __hip_bfloat16* proj_f   = (__hip_bfloat16*)(ws + 226713600);     // 73728 B
    __hip_bfloat16* W1f      = (__hip_bfloat16*)(ws + 226787328);     // 294912 B
    __hip_bfloat16* W2f      = (__hip_bfloat16*)(ws + 227082240);     // 294912 B
    float*          bias_g   = (float*)         (ws + 227377152);     // 393216 B
    __hip_bfloat16* Og       = (__hip_bfloat16*)(ws + 227770368);     // 56623104 B
    int*            map      = (int*)           (ws + 284393472);     // 589824 B
    float*          mg       = (float*)         (ws + 284983296);     // 3538944 B

    ln1_kernel<<<(2*NSIDE_TOK)/4, 256, 0, stream>>>(x_left, x_right, n1g, n1b, xln_all);

    conv_w_kernel<<<1728, 256, 0, stream>>>(q_w, kv_w, proj_w, fc1_w, fc2_w,
                                            q_wf, kv_wf, proj_f, W1f, W2f);
    bias_setup_kernel<<<96, 256, 0, stream>>>(bias_table, bias_g);
    map_kernel<<<(2*NSIDE_TOK)/256, 256, 0, stream>>>(d_left, d_right, map);

    // KV = gather(xln) @ kv_w + kv_b  (A gathered through map)
    proj_gemm_kernel<24><<<(2*NSIDE_TOK)/64, 256, 0, stream>>>(
        xln_all, kv_wf, kv_b, map, KVg, 1.0f);
    // Q = (xln @ q_w + q_b) * scale
    proj_gemm_kernel<12><<<(2*NSIDE_TOK)/64, 256, 0, stream>>>(
        xln_all, q_wf, q_b, nullptr, Qg, 0.17677669529663687f);

    attn_pm_kernel<<<BWIN*NHEADS, 128, 0, stream>>>(Qg, KVg, bias_g, Og, mg);

    projfuse_kernel<<<2*BWIN, 256, 0, stream>>>(
        Og, proj_f, proj_b, mg, xln_all, x_left, x_right, n2g, n2b, out, xln2);

    mlp_mfma_kernel<<<(2*NSIDE_TOK)/64, 256, 0, stream>>>(
        out, xln2, W1f, fc1_b, W2f, fc2_b);
}

// Round 14
// 534.889 us; speedup vs baseline: 1.0273x; 1.0273x over previous
//
#include <hip/hip_runtime.h>
#include <hip/hip_bf16.h>

#define BB 2
#define HH 192
#define WIMG 192
#define CC 192
#define NHEADS 6
#define HD 32
#define NTOK (HH*WIMG)        // 36864 tokens per image
#define NWX 24                // windows per axis
#define NWIN 576
#define BWIN (BB*NWIN)        // 1152
#define MLPH 768
#define EPS_ 1e-5f
#define NSIDE_TOK (BB*NTOK)   // 73728 tokens per side

typedef __attribute__((ext_vector_type(8))) short bf16x8;
typedef __attribute__((ext_vector_type(4))) float f32x4;

#define GLOBAL_AS __attribute__((address_space(1)))
#define LDS_AS __attribute__((address_space(3)))
__device__ __forceinline__ void gll16(const void* g, void* l) {
    __builtin_amdgcn_global_load_lds((const GLOBAL_AS unsigned int*)g,
                                     (LDS_AS unsigned int*)l, 16, 0, 0);
}

__device__ __forceinline__ unsigned short f2bf(float f) {
    __hip_bfloat16 h = __float2bfloat16(f);
    return *reinterpret_cast<unsigned short*>(&h);
}
__device__ __forceinline__ float bfu(unsigned short u) {
    return __uint_as_float(((unsigned int)u) << 16);
}
// tanh-form GELU (max |err| vs exact ~3e-3; threshold 0.18)
__device__ __forceinline__ float gelu_fast(float x) {
    float z = 1.5957691216f*(x + 0.044715f*x*x*x);
    float e = __expf(z);
    float t = 1.0f - 2.0f/(e + 1.0f);
    return 0.5f*x*(1.0f + t);
}
// shifted-window token index for window (wi,wj), position p in [0,64)
__device__ __forceinline__ int tokof(int b, int wi, int wj, int p) {
    int rh = wi*8 + (p>>3), rw = wj*8 + (p&7);
    int i = rh + 4; if (i >= HH) i -= HH;
    int j = rw + 4; if (j >= WIMG) j -= WIMG;
    return b*NTOK + i*WIMG + j;
}

// ---------------- K1: LayerNorm1 -> bf16 ----------------
__global__ __launch_bounds__(256) void ln1_kernel(
    const float* __restrict__ xl, const float* __restrict__ xr,
    const float* __restrict__ g, const float* __restrict__ bta,
    __hip_bfloat16* __restrict__ xln_all)
{
    int token = blockIdx.x*4 + (threadIdx.x >> 6);
    int lane = threadIdx.x & 63;
    const float* src;
    __hip_bfloat16* dst;
    if (token < NSIDE_TOK) { src = xl + (size_t)token*CC; dst = xln_all + (size_t)token*CC; }
    else { int t2 = token - NSIDE_TOK; src = xr + (size_t)t2*CC; dst = xln_all + (size_t)token*CC; }
    float v0 = src[lane], v1 = src[lane+64], v2 = src[lane+128];
    float s = v0+v1+v2;
    float q = v0*v0 + v1*v1 + v2*v2;
    #pragma unroll
    for (int m = 32; m; m >>= 1) { s += __shfl_xor(s, m, 64); q += __shfl_xor(q, m, 64); }
    float mu = s * (1.0f/CC);
    float inv = rsqrtf(fmaxf(q*(1.0f/CC) - mu*mu, 0.0f) + EPS_);
    dst[lane]     = __float2bfloat16((v0-mu)*inv*g[lane]     + bta[lane]);
    dst[lane+64]  = __float2bfloat16((v1-mu)*inv*g[lane+64]  + bta[lane+64]);
    dst[lane+128] = __float2bfloat16((v2-mu)*inv*g[lane+128] + bta[lane+128]);
}

// ---------------- K2: epipolar gather index map ----------------
__global__ __launch_bounds__(256) void map_kernel(
    const float* __restrict__ d_left, const float* __restrict__ d_right,
    int* __restrict__ map)
{
    int gid = blockIdx.x*256 + threadIdx.x;      // 0 .. 2*73728
    int side = (gid >= NSIDE_TOK) ? 1 : 0;
    int row = gid - side*NSIDE_TOK;
    int j = row % WIMG;
    float d = side ? d_right[row] : d_left[row];
    int jj;
    if (!side) { float f = (float)j + 0.5f - d; f = fmaxf(f, 0.f); jj = (int)f; }
    else       { float f = (float)j + 0.5f + d; f = fminf(f, 191.f); jj = (int)f; }
    map[gid] = (side ? 0 : NSIDE_TOK) + row - j + jj;
}

// ---------------- K3: convert weights to bf16 MFMA-FRAGMENT order ----------
__global__ __launch_bounds__(256) void conv_w_kernel(
    const float* __restrict__ q_w, const float* __restrict__ kv_w,
    const float* __restrict__ proj_w, const float* __restrict__ fc1_w,
    const float* __restrict__ fc2_w,
    __hip_bfloat16* __restrict__ q_wf, __hip_bfloat16* __restrict__ kv_wf,
    __hip_bfloat16* __restrict__ proj_f, __hip_bfloat16* __restrict__ W1f,
    __hip_bfloat16* __restrict__ W2f)
{
    int idx = blockIdx.x*256 + threadIdx.x;   // total 442368
    if (idx < 36864) {
        int j = idx & 7, lane = (idx>>3) & 63, fr = idx>>9;
        int ct = fr % 12, ks = fr / 12;
        int n = ct*16 + (lane&15), k = ks*32 + (lane>>4)*8 + j;
        q_wf[idx] = __float2bfloat16(q_w[(size_t)k*192 + n]);
    } else if (idx < 110592) {
        int i2 = idx - 36864;
        int j = i2 & 7, lane = (i2>>3) & 63, fr = i2>>9;
        int ct = fr % 24, ks = fr / 24;
        int n = ct*16 + (lane&15), k = ks*32 + (lane>>4)*8 + j;
        kv_wf[i2] = __float2bfloat16(kv_w[(size_t)k*384 + n]);
    } else if (idx < 147456) {
        int i2 = idx - 110592;
        int j = i2 & 7, lane = (i2>>3) & 63, fr = i2>>9;
        int ct = fr % 12, h = fr / 12;
        int n = ct*16 + (lane&15), k = h*32 + (lane>>4)*8 + j;
        proj_f[i2] = __float2bfloat16(proj_w[(size_t)k*192 + n]);
    } else if (idx < 294912) {
        // W1f: frag = (cc2*6 + ks)*2 + ct,  cc2 in [0,24), ct in [0,2)
        int i2 = idx - 147456;
        int j = i2 & 7, lane = (i2>>3) & 63, fr = i2>>9;
        int ct = fr & 1, ks = (fr>>1) % 6, cc2 = fr / 12;
        int n = cc2*32 + ct*16 + (lane&15), k = ks*32 + (lane>>4)*8 + j;
        W1f[i2] = __float2bfloat16(fc1_w[(size_t)k*MLPH + n]);
    } else {
        // W2f: frag = (cc*2+ks)*12+ct
        int i2 = idx - 294912;
        int j = i2 & 7, lane = (i2>>3) & 63, fr = i2>>9;
        int ct = fr % 12, ks = (fr/12) % 2, cc = fr / 24;
        int n = ct*16 + (lane&15), k = cc*64 + ks*32 + (lane>>4)*8 + j;
        W2f[i2] = __float2bfloat16(fc2_w[(size_t)k*192 + n]);
    }
}

// ---------------- K4: per-head rel-pos bias matrix [6][64][64] f32 ----------
__global__ __launch_bounds__(256) void bias_setup_kernel(
    const float* __restrict__ table, float* __restrict__ bias_glob)
{
    int idx = blockIdx.x*256 + threadIdx.x;   // 24576
    int h = idx >> 12, rem = idx & 4095;
    int q = rem >> 6, k = rem & 63;
    int qy = q>>3, qx = q&7, ky = k>>3, kx = k&7;
    int ridx = (qy-ky+7)*15 + (qx-kx+7);
    bias_glob[idx] = table[ridx*NHEADS + h];
}

// ---------------- K5: bf16 MFMA projection GEMM (A in regs, W staged in LDS)
template<int NT>
__global__ __launch_bounds__(256) void proj_gemm_kernel(
    const __hip_bfloat16* __restrict__ in, const __hip_bfloat16* __restrict__ Wf,
    const float* __restrict__ bias, const int* __restrict__ map,
    __hip_bfloat16* __restrict__ outp, float scale)
{
    __shared__ unsigned short wst[2][NT*512];
    const int tid = threadIdx.x, lane = tid & 63, w = tid >> 6;
    const int r16 = lane & 15, kg = lane >> 4, w16 = w*16;
    const size_t baserow = (size_t)blockIdx.x * 64;
    const int row = (int)baserow + w16 + r16;
    const size_t arow = map ? (size_t)map[row] : (size_t)row;

    bf16x8 aReg[6];
    #pragma unroll
    for (int ks = 0; ks < 6; ++ks)
        aReg[ks] = *reinterpret_cast<const bf16x8*>(in + arow*CC + ks*32 + kg*8);

    const char* wsrc = (const char*)Wf;
    const int soff = w*1024 + lane*16;
    #pragma unroll
    for (int i = 0; i < NT/4; ++i)
        gll16(wsrc + i*4096 + soff, (char*)wst[0] + i*4096 + w*1024);

    f32x4 acc[NT];
    #pragma unroll
    for (int ct = 0; ct < NT; ++ct) { float bv = bias[ct*16+r16]; acc[ct] = (f32x4){bv,bv,bv,bv}; }

    #pragma unroll
    for (int ks = 0; ks < 6; ++ks) {
        __syncthreads();
        if (ks < 5) {
            const char* s2 = wsrc + (size_t)(ks+1)*NT*1024;
            #pragma unroll
            for (int i = 0; i < NT/4; ++i)
                gll16(s2 + i*4096 + soff, (char*)wst[(ks+1)&1] + i*4096 + w*1024);
        }
        #pragma unroll
        for (int ct = 0; ct < NT; ++ct) {
            bf16x8 bb = *reinterpret_cast<const bf16x8*>(wst[ks&1] + ct*512 + lane*8);
            acc[ct] = __builtin_amdgcn_mfma_f32_16x16x32_bf16(aReg[ks], bb, acc[ct], 0, 0, 0);
        }
    }
    const int ldo = NT*16;
    #pragma unroll
    for (int ct = 0; ct < NT; ++ct)
        #pragma unroll
        for (int r = 0; r < 4; ++r)
            outp[(baserow + w16 + kg*4 + r)*ldo + ct*16 + r16] =
                __float2bfloat16(acc[ct][r] * scale);
}

// ---------------- K6: window attention + m, one barrier ---------------------
__global__ __launch_bounds__(128) void attn_pm_kernel(
    const __hip_bfloat16* __restrict__ Qglob,   // [2][73728][192]
    const __hip_bfloat16* __restrict__ KVglob,  // [2][73728][384]
    const float* __restrict__ bias_glob,        // [6][64][64]
    __hip_bfloat16* __restrict__ Og,            // [2*1152*64][192]
    float* __restrict__ mg)                     // [2][1152][6][64]
{
    __shared__ unsigned short Pl[2][64*72];
    __shared__ unsigned short Vl[2][32*72];
    const int tid = threadIdx.x, lane = tid & 63, s = tid >> 6;
    const int r16 = lane & 15, kg = lane >> 4;
    const int bid = blockIdx.x;
    const int wd = bid / NHEADS, h = bid % NHEADS;
    const int b = wd / NWIN, win = wd % NWIN;
    const int wi = win / NWX, wj = win % NWX;
    const bool edge_i = (wi == NWX-1), edge_j = (wj == NWX-1);

    const __hip_bfloat16* Qs  = Qglob  + (size_t)s*NSIDE_TOK*CC;
    const __hip_bfloat16* KVs = KVglob + (size_t)s*NSIDE_TOK*(2*CC);

    int tokQ[4];
    #pragma unroll
    for (int mi = 0; mi < 4; ++mi) tokQ[mi] = tokof(b, wi, wj, mi*16 + r16);
    const int tokV = tokof(b, wi, wj, lane);

    unsigned short* P = Pl[s];
    unsigned short* V = Vl[s];

    // ---- stage V^T (wave-private)
    {
        bf16x8 vv[4];
        #pragma unroll
        for (int dg = 0; dg < 4; ++dg)
            vv[dg] = *reinterpret_cast<const bf16x8*>(
                KVs + (size_t)tokV*(2*CC) + CC + h*HD + dg*8);
        #pragma unroll
        for (int dg = 0; dg < 4; ++dg)
            #pragma unroll
            for (int jj = 0; jj < 8; ++jj)
                V[(dg*8+jj)*72 + lane] = (unsigned short)vv[dg][jj];
    }

    // ---- S = Q K^T
    bf16x8 aQ[4], bK[4];
    #pragma unroll
    for (int mi = 0; mi < 4; ++mi)
        aQ[mi] = *reinterpret_cast<const bf16x8*>(
            Qs + (size_t)tokQ[mi]*CC + h*HD + kg*8);
    #pragma unroll
    for (int ni = 0; ni < 4; ++ni)
        bK[ni] = *reinterpret_cast<const bf16x8*>(
            KVs + (size_t)tokQ[ni]*(2*CC) + h*HD + kg*8);
    f32x4 S[4][4];
    #pragma unroll
    for (int mi = 0; mi < 4; ++mi)
        #pragma unroll
        for (int ni = 0; ni < 4; ++ni)
            S[mi][ni] = __builtin_amdgcn_mfma_f32_16x16x32_bf16(
                aQ[mi], bK[ni], (f32x4){0.f,0.f,0.f,0.f}, 0, 0, 0);

    // ---- bias + shift mask
    #pragma unroll
    for (int mi = 0; mi < 4; ++mi)
        #pragma unroll
        for (int ni = 0; ni < 4; ++ni)
            #pragma unroll
            for (int rr = 0; rr < 4; ++rr) {
                int q = mi*16 + kg*4 + rr, k = ni*16 + r16;
                float bm = bias_glob[h*4096 + q*64 + k];
                int qy = q>>3, qx = q&7, ky = k>>3, kx = k&7;
                bool msk = (edge_i && ((qy<4) != (ky<4))) ||
                           (edge_j && ((qx<4) != (kx<4)));
                S[mi][ni][rr] += bm + (msk ? -100.0f : 0.0f);
            }

    // ---- softmax over k
    float mx[4][4], sm[4][4];
    #pragma unroll
    for (int mi = 0; mi < 4; ++mi)
        #pragma unroll
        for (int rr = 0; rr < 4; ++rr)
            mx[mi][rr] = fmaxf(fmaxf(S[mi][0][rr], S[mi][1][rr]),
                               fmaxf(S[mi][2][rr], S[mi][3][rr]));
    #pragma unroll
    for (int m = 1; m <= 8; m <<= 1)
        #pragma unroll
        for (int mi = 0; mi < 4; ++mi)
            #pragma unroll
            for (int rr = 0; rr < 4; ++rr)
                mx[mi][rr] = fmaxf(mx[mi][rr], __shfl_xor(mx[mi][rr], m, 64));
    #pragma unroll
    for (int mi = 0; mi < 4; ++mi)
        #pragma unroll
        for (int rr = 0; rr < 4; ++rr) sm[mi][rr] = 0.f;
    #pragma unroll
    for (int mi = 0; mi < 4; ++mi)
        #pragma unroll
        for (int ni = 0; ni < 4; ++ni)
            #pragma unroll
            for (int rr = 0; rr < 4; ++rr) {
                S[mi][ni][rr] = __expf(S[mi][ni][rr] - mx[mi][rr]);
                sm[mi][rr] += S[mi][ni][rr];
            }
    #pragma unroll
    for (int m = 1; m <= 8; m <<= 1)
        #pragma unroll
        for (int mi = 0; mi < 4; ++mi)
            #pragma unroll
            for (int rr = 0; rr < 4; ++rr)
                sm[mi][rr] += __shfl_xor(sm[mi][rr], m, 64);
    #pragma unroll
    for (int mi = 0; mi < 4; ++mi)
        #pragma unroll
        for (int rr = 0; rr < 4; ++rr) sm[mi][rr] = 1.0f / sm[mi][rr];

    // ---- P -> LDS (72-stride rows)
    #pragma unroll
    for (int mi = 0; mi < 4; ++mi)
        #pragma unroll
        for (int ni = 0; ni < 4; ++ni)
            #pragma unroll
            for (int rr = 0; rr < 4; ++rr)
                P[(mi*16 + kg*4 + rr)*72 + ni*16 + r16] =
                    f2bf(S[mi][ni][rr] * sm[mi][rr]);

    // ---- PV (own P, own V^T)
    {
        f32x4 O[4][2];
        #pragma unroll
        for (int mi = 0; mi < 4; ++mi)
            #pragma unroll
            for (int dt = 0; dt < 2; ++dt) O[mi][dt] = (f32x4){0.f,0.f,0.f,0.f};
        #pragma unroll
        for (int ks = 0; ks < 2; ++ks) {
            bf16x8 aP[4], bV[2];
            #pragma unroll
            for (int mi = 0; mi < 4; ++mi)
                aP[mi] = *reinterpret_cast<const bf16x8*>(
                    P + (mi*16 + r16)*72 + ks*32 + kg*8);
            #pragma unroll
            for (int dt = 0; dt < 2; ++dt)
                bV[dt] = *reinterpret_cast<const bf16x8*>(
                    V + (dt*16 + r16)*72 + ks*32 + kg*8);
            #pragma unroll
            for (int mi = 0; mi < 4; ++mi)
                #pragma unroll
                for (int dt = 0; dt < 2; ++dt)
                    O[mi][dt] = __builtin_amdgcn_mfma_f32_16x16x32_bf16(
                        aP[mi], bV[dt], O[mi][dt], 0, 0, 0);
        }
        __hip_bfloat16* ob = Og + ((size_t)(s*BWIN + wd)*64)*CC + h*HD;
        #pragma unroll
        for (int mi = 0; mi < 4; ++mi)
            #pragma unroll
            for (int dt = 0; dt < 2; ++dt)
                #pragma unroll
                for (int rr = 0; rr < 4; ++rr)
                    ob[(size_t)(mi*16 + kg*4 + rr)*CC + dt*16 + r16] =
                        __float2bfloat16(O[mi][dt][rr]);
    }

    __syncthreads();   // both waves' P visible

    // ---- m: wave s computes m for side s (P at native 72 stride)
    {
        const unsigned short* Pa = Pl[s];
        const unsigned short* Pb = Pl[s^1];
        const int i = lane;
        const int s0 = (i >= 2) ? -2 : -i;
        const int s1 = (i <= 61) ? 2 : 63 - i;
        float acc = 0.f;
        for (int k = 0; k < 64; k += 2) {
            float pb0 = bfu(Pb[k*72 + i]);
            float pb1 = bfu(Pb[(k+1)*72 + i]);
            float a0 = 0.f, a1 = 0.f;
            for (int ss = s0; ss <= s1; ++ss) {
                unsigned int pr = *reinterpret_cast<const unsigned int*>(
                    &Pa[(i+ss)*72 + k]);
                a0 += bfu((unsigned short)(pr & 0xffff));
                a1 += bfu((unsigned short)(pr >> 16));
            }
            acc += a0*pb0 + a1*pb1;
        }
        float e = __expf(10.0f * acc);           // tanh(5a), a >= 0
        mg[((size_t)(s*BWIN + wd)*NHEADS + h)*64 + i] = 1.0f - 2.0f/(e + 1.0f);
    }
}

// ---------------- K7: proj + fuse + reverse + residual + LN2 -> xln2 --------
__global__ __launch_bounds__(256) void projfuse_kernel(
    const __hip_bfloat16* __restrict__ Og,
    const __hip_bfloat16* __restrict__ proj_f,
    const float* __restrict__ proj_b,
    const float* __restrict__ mg,
    const __hip_bfloat16* __restrict__ xln_all,
    const float* __restrict__ x_left, const float* __restrict__ x_right,
    const float* __restrict__ g2, const float* __restrict__ b2,
    float* __restrict__ out, __hip_bfloat16* __restrict__ xln2)
{
    __shared__ unsigned short wst[2][12*512];
    const int tid = threadIdx.x, lane = tid & 63, w = tid >> 6;
    const int r16 = lane & 15, kg = lane >> 4, w16 = w*16;
    const int bid = blockIdx.x;
    const int s = bid / BWIN, wd = bid % BWIN;
    const int b = wd / NWIN, win = wd % NWIN;
    const int wi = win / NWX, wj = win % NWX;

    const size_t orow = (size_t)(s*BWIN + wd)*64 + w16 + r16;
    bf16x8 aReg[6];
    #pragma unroll
    for (int ks = 0; ks < 6; ++ks)
        aReg[ks] = *reinterpret_cast<const bf16x8*>(Og + orow*CC + ks*32 + kg*8);

    const char* wsrc = (const char*)proj_f;
    const int soff = w*1024 + lane*16;
    #pragma unroll
    for (int i = 0; i < 3; ++i)
        gll16(wsrc + i*4096 + soff, (char*)wst[0] + i*4096 + w*1024);

    f32x4 acc[12];
    #pragma unroll
    for (int ct = 0; ct < 12; ++ct) { float bv = proj_b[ct*16+r16]; acc[ct] = (f32x4){bv,bv,bv,bv}; }

    #pragma unroll
    for (int ks = 0; ks < 6; ++ks) {
        __syncthreads();
        if (ks < 5) {
            const char* s2 = wsrc + (size_t)(ks+1)*12288;
            #pragma unroll
            for (int i = 0; i < 3; ++i)
                gll16(s2 + i*4096 + soff, (char*)wst[(ks+1)&1] + i*4096 + w*1024);
        }
        #pragma unroll
        for (int ct = 0; ct < 12; ++ct) {
            bf16x8 bb = *reinterpret_cast<const bf16x8*>(wst[ks&1] + ct*512 + lane*8);
            acc[ct] = __builtin_amdgcn_mfma_f32_16x16x32_bf16(aReg[ks], bb, acc[ct], 0, 0, 0);
        }
    }

    // ---- epilogue: fuse + window reverse + residual (keep values in acc)
    int tk[4];
    #pragma unroll
    for (int rr = 0; rr < 4; ++rr) tk[rr] = tokof(b, wi, wj, w16 + kg*4 + rr);
    const float* xo_s = s ? x_right : x_left;
    const __hip_bfloat16* xw_s = xln_all + (size_t)s*NSIDE_TOK*CC;
    float* out_s = out + (size_t)s*NSIDE_TOK*CC;
    __hip_bfloat16* xln2_s = xln2 + (size_t)s*NSIDE_TOK*CC;
    const float* mrow = mg + (size_t)(s*BWIN + wd)*NHEADS*64;

    float g2c[12], b2c[12];
    #pragma unroll
    for (int ct = 0; ct < 12; ++ct) {
        g2c[ct] = g2[ct*16 + r16];
        b2c[ct] = b2[ct*16 + r16];
    }

    #pragma unroll
    for (int ct = 0; ct < 12; ++ct) {
        int col = ct*16 + r16;
        int h = ct >> 1;
        #pragma unroll
        for (int rr = 0; rr < 4; ++rr) {
            int q = w16 + kg*4 + rr;
            size_t tt = (size_t)tk[rr];
            float m = mrow[h*64 + q];
            float xw = __bfloat162float(xw_s[tt*CC + col]);
            float p = acc[ct][rr];
            float val = xo_s[tt*CC + col] + xw + (p - xw)*m;
            out_s[tt*CC + col] = val;
            acc[ct][rr] = val;
        }
    }

    // ---- LN2 of fused output -> bf16 xln2 (stats via 16-lane shuffles)
    #pragma unroll
    for (int rr = 0; rr < 4; ++rr) {
        float sum = 0.f, sq = 0.f;
        #pragma unroll
        for (int ct = 0; ct < 12; ++ct) {
            float v = acc[ct][rr];
            sum += v; sq += v*v;
        }
        #pragma unroll
        for (int m = 1; m <= 8; m <<= 1) {
            sum += __shfl_xor(sum, m, 64);
            sq  += __shfl_xor(sq,  m, 64);
        }
        float mu = sum * (1.0f/CC);
        float inv = rsqrtf(fmaxf(sq*(1.0f/CC) - mu*mu, 0.0f) + EPS_);
        size_t tt = (size_t)tk[rr];
        #pragma unroll
        for (int ct = 0; ct < 12; ++ct) {
            unsigned short uv = f2bf((acc[ct][rr]-mu)*inv*g2c[ct] + b2c[ct]);
            *reinterpret_cast<unsigned short*>(&xln2_s[tt*CC + ct*16 + r16]) = uv;
        }
    }
}

// ---------------- K8: fused MLP — R12 per-wave structure, 512 threads -------
// Two 64-token tile groups per block share one weight staging: waves 0-3 ->
// tile A, waves 4-7 -> tile B. 12KB chunk staged once per 128 tokens by waves
// 0-2 (4 issues each). Occupancy: LDS 43KB -> 3 blocks/CU = 24 waves/CU.
__global__ __launch_bounds__(512) void mlp_mfma_kernel(
    float* __restrict__ out, const __hip_bfloat16* __restrict__ xln2,
    const __hip_bfloat16* __restrict__ W1f, const float* __restrict__ fc1_b,
    const __hip_bfloat16* __restrict__ W2f, const float* __restrict__ fc2_b)
{
    __shared__ unsigned short hbuf[2][64*72];  // per tile group
    __shared__ unsigned short wst[2][6144];    // 2 x 12288 B weight staging
    const int tid  = threadIdx.x;
    const int lane = tid & 63;
    const int w    = tid >> 6;        // 0..7
    const int tg   = w >> 2;          // tile group 0/1
    const int w4   = w & 3;
    const int r16 = lane & 15, kg = lane >> 4, w16 = w4*16;
    const size_t base = (size_t)blockIdx.x * 128 * CC + (size_t)tg * 64 * CC;

    bf16x8 aReg[6];
    #pragma unroll
    for (int ks = 0; ks < 6; ++ks)
        aReg[ks] = *reinterpret_cast<const bf16x8*>(
            xln2 + base + (size_t)(w16 + r16)*CC + ks*32 + kg*8);

    const char* W1c = (const char*)W1f;
    const char* W2c = (const char*)W2f;
    const int soff = w*4096 + lane*16;   // staging waves w<3 each cover 4KB x4
    const int doff = w*4096;
    unsigned short* hb = hbuf[tg];

    // prologue: stage W1 chunk 0 -> wst[0]
    if (w < 3) {
        #pragma unroll
        for (int i = 0; i < 4; ++i)
            gll16(W1c + i*1024 + soff, (char*)wst[0] + i*1024 + doff);
    }

    f32x4 acc2[12];
    #pragma unroll
    for (int i = 0; i < 12; ++i) acc2[i] = (f32x4){0.f,0.f,0.f,0.f};

    for (int cc = 0; cc < 12; ++cc) {
        f32x4 acc1[4];
        // ---- q0: stage W1 chunk 2cc+1 -> wst[1]; compute fc1 half from wst[0]
        __builtin_amdgcn_s_barrier();
        if (w < 3) {
            const char* s2 = W1c + (size_t)(2*cc+1)*12288;
            #pragma unroll
            for (int i = 0; i < 4; ++i)
                gll16(s2 + i*1024 + soff, (char*)wst[1] + i*1024 + doff);
        }
        asm volatile("s_waitcnt vmcnt(4)" ::: "memory");
        __builtin_amdgcn_s_barrier();
        #pragma unroll
        for (int c2 = 0; c2 < 2; ++c2) {
            float bv = fc1_b[cc*64 + c2*16 + r16];
            acc1[c2] = (f32x4){bv,bv,bv,bv};
        }
        #pragma unroll
        for (int ks = 0; ks < 6; ++ks)
            #pragma unroll
            for (int c2 = 0; c2 < 2; ++c2) {
                bf16x8 bw = *reinterpret_cast<const bf16x8*>(wst[0] + (ks*2+c2)*512 + lane*8);
                acc1[c2] = __builtin_amdgcn_mfma_f32_16x16x32_bf16(aReg[ks], bw, acc1[c2], 0, 0, 0);
            }
        // ---- q1: stage W2 chunk 2cc -> wst[0]; compute fc1 half2 from wst[1]
        __builtin_amdgcn_s_barrier();
        if (w < 3) {
            const char* s2 = W2c + (size_t)(2*cc)*12288;
            #pragma unroll
            for (int i = 0; i < 4; ++i)
                gll16(s2 + i*1024 + soff, (char*)wst[0] + i*1024 + doff);
        }
        asm volatile("s_waitcnt vmcnt(4)" ::: "memory");
        __builtin_amdgcn_s_barrier();
        #pragma unroll
        for (int c2 = 0; c2 < 2; ++c2) {
            float bv = fc1_b[cc*64 + 32 + c2*16 + r16];
            acc1[2+c2] = (f32x4){bv,bv,bv,bv};
        }
        #pragma unroll
        for (int ks = 0; ks < 6; ++ks)
            #pragma unroll
            for (int c2 = 0; c2 < 2; ++c2) {
                bf16x8 bw = *reinterpret_cast<const bf16x8*>(wst[1] + (ks*2+c2)*512 + lane*8);
                acc1[2+c2] = __builtin_amdgcn_mfma_f32_16x16x32_bf16(aReg[ks], bw, acc1[2+c2], 0, 0, 0);
            }
        // GELU -> hbuf (wave-private rows within tile group)
        #pragma unroll
        for (int ct = 0; ct < 4; ++ct)
            #pragma unroll
            for (int r = 0; r < 4; ++r)
                hb[(w16 + kg*4 + r)*72 + ct*16 + r16] = f2bf(gelu_fast(acc1[ct][r]));
        // ---- q2: stage W2 chunk 2cc+1 -> wst[1]; compute fc2 ks0 from wst[0]
        __builtin_amdgcn_s_barrier();
        if (w < 3) {
            const char* s2 = W2c + (size_t)(2*cc+1)*12288;
            #pragma unroll
            for (int i = 0; i < 4; ++i)
                gll16(s2 + i*1024 + soff, (char*)wst[1] + i*1024 + doff);
        }
        asm volatile("s_waitcnt vmcnt(4)" ::: "memory");
        __builtin_amdgcn_s_barrier();
        {
            bf16x8 aP = *reinterpret_cast<const bf16x8*>(hb + (w16+r16)*72 + kg*8);
            #pragma unroll
            for (int ct = 0; ct < 12; ++ct) {
                bf16x8 bw = *reinterpret_cast<const bf16x8*>(wst[0] + ct*512 + lane*8);
                acc2[ct] = __builtin_amdgcn_mfma_f32_16x16x32_bf16(aP, bw, acc2[ct], 0, 0, 0);
            }
        }
        // ---- q3: stage W1 chunk 2cc+2 -> wst[0]; compute fc2 ks1 from wst[1]
        __builtin_amdgcn_s_barrier();
        if (cc < 11) {
            if (w < 3) {
                const char* s2 = W1c + (size_t)(2*cc+2)*12288;
                #pragma unroll
                for (int i = 0; i < 4; ++i)
                    gll16(s2 + i*1024 + soff, (char*)wst[0] + i*1024 + doff);
            }
            asm volatile("s_waitcnt vmcnt(4)" ::: "memory");
        } else {
            asm volatile("s_waitcnt vmcnt(0)" ::: "memory");
        }
        __builtin_amdgcn_s_barrier();
        {
            bf16x8 aP = *reinterpret_cast<const bf16x8*>(hb + (w16+r16)*72 + 32 + kg*8);
            #pragma unroll
            for (int ct = 0; ct < 12; ++ct) {
                bf16x8 bw = *reinterpret_cast<const bf16x8*>(wst[1] + ct*512 + lane*8);
                acc2[ct] = __builtin_amdgcn_mfma_f32_16x16x32_bf16(aP, bw, acc2[ct], 0, 0, 0);
            }
        }
    }

    // epilogue: out += mlp + fc2_b
    #pragma unroll
    for (int ct = 0; ct < 12; ++ct) {
        int col = ct*16 + r16;
        float bv = fc2_b[col];
        #pragma unroll
        for (int r = 0; r < 4; ++r) {
            size_t idx = base + (size_t)(w16 + kg*4 + r)*CC + col;
            out[idx] = out[idx] + acc2[ct][r] + bv;
        }
    }
}

// ---------------- launch ----------------
extern "C" void kernel_launch(void* const* d_in, const int* in_sizes, int n_in,
                              void* d_out, int out_size, void* d_ws, size_t ws_size,
                              hipStream_t stream)
{
    (void)in_sizes; (void)n_in; (void)out_size; (void)ws_size;
    const float* x_left  = (const float*)d_in[0];
    const float* x_right = (const float*)d_in[1];
    const float* d_left  = (const float*)d_in[2];
    const float* d_right = (const float*)d_in[3];
    const float* n1g = (const float*)d_in[4];
    const float* n1b = (const float*)d_in[5];
    const float* q_w = (const float*)d_in[6];
    const float* q_b = (const float*)d_in[7];
    const float* kv_w = (const float*)d_in[8];
    const float* kv_b = (const float*)d_in[9];
    const float* proj_w = (const float*)d_in[10];
    const float* proj_b = (const float*)d_in[11];
    const float* bias_table = (const float*)d_in[12];
    const float* n2g = (const float*)d_in[13];
    const float* n2b = (const float*)d_in[14];
    const float* fc1_w = (const float*)d_in[15];
    const float* fc1_b = (const float*)d_in[16];
    const float* fc2_w = (const float*)d_in[17];
    const float* fc2_b = (const float*)d_in[18];
    float* out = (float*)d_out;

    char* ws = (char*)d_ws;
    __hip_bfloat16* xln_all  = (__hip_bfloat16*)(ws);                 // 56623104 B
    __hip_bfloat16* Qg       = (__hip_bfloat16*)(ws + 56623104);      // 56623104 B
    __hip_bfloat16* KVg      = (__hip_bfloat16*)(ws + 113246208);     // 113246208 B
    __hip_bfloat16* xln2     = (__hip_bfloat16*)(ws + 113246208);     // aliases KVg (dead after attn)
    __hip_bfloat16* q_wf     = (__hip_bfloat16*)(ws + 226492416);     // 73728 B
    __hip_bfloat16* kv_wf    = (__hip_bfloat16*)(ws + 226566144);     // 147456 B
    __hip_bfloat16* proj_f   = (__hip_bfloat16*)(ws + 226713600);     // 73728 B
    __hip_bfloat16* W1f      = (__hip_bfloat16*)(ws + 226787328);     // 294912 B
    __hip_bfloat16* W2f      = (__hip_bfloat16*)(ws + 227082240);     // 294912 B
    float*          bias_g   = (float*)         (ws + 227377152);     // 393216 B
    __hip_bfloat16* Og       = (__hip_bfloat16*)(ws + 227770368);     // 56623104 B
    int*            map      = (int*)           (ws + 284393472);     // 589824 B
    float*          mg       = (float*)         (ws + 284983296);     // 3538944 B

    ln1_kernel<<<(2*NSIDE_TOK)/4, 256, 0, stream>>>(x_left, x_right, n1g, n1b, xln_all);

    conv_w_kernel<<<1728, 256, 0, stream>>>(q_w, kv_w, proj_w, fc1_w, fc2_w,
                                            q_wf, kv_wf, proj_f, W1f, W2f);
    bias_setup_kernel<<<96, 256, 0, stream>>>(bias_table, bias_g);
    map_kernel<<<(2*NSIDE_TOK)/256, 256, 0, stream>>>(d_left, d_right, map);

    // KV = gather(xln) @ kv_w + kv_b  (A gathered through map)
    proj_gemm_kernel<24><<<(2*NSIDE_TOK)/64, 256, 0, stream>>>(
        xln_all, kv_wf, kv_b, map, KVg, 1.0f);
    // Q = (xln @ q_w + q_b) * scale
    proj_gemm_kernel<12><<<(2*NSIDE_TOK)/64, 256, 0, stream>>>(
        xln_all, q_wf, q_b, nullptr, Qg, 0.17677669529663687f);

    attn_pm_kernel<<<BWIN*NHEADS, 128, 0, stream>>>(Qg, KVg, bias_g, Og, mg);

    projfuse_kernel<<<2*BWIN, 256, 0, stream>>>(
        Og, proj_f, proj_b, mg, xln_all, x_left, x_right, n2g, n2b, out, xln2);

    mlp_mfma_kernel<<<(2*NSIDE_TOK)/128, 512, 0, stream>>>(
        out, xln2, W1f, fc1_b, W2f, fc2_b);
}